// Round 16
// baseline (132.008 us; speedup 1.0000x reference)
//
#include <hip/hip_runtime.h>
#include <math.h>

#define D 256
#define B 16
#define L 8
#define N 128

static constexpr float LAMBDA_ASYNC = 0.08f;
static constexpr float LAMBDA_TAU   = 0.12f;

// ws layout (floats) — single rotating buffers (stream strictly serial):
//   acct[4096]   @ 0      (pre-scaled vin [d][b]; xt for l==0)
//   colsum[256]  @ 4096
//   meta[16]     @ 4352   (meta[0] = fired count of previous layer)
//   fired[128]   @ 4368
//   slab[128][4096] @ 4496  (per-node tanh'd tiles, [e][b]; 2 MB)
// Branchless masking in reduce (poison 0xAA is finite; fired=0 kills it).

#define OFF_COLSUM 4096
#define OFF_META   4352
#define OFF_FIRED  4368
#define OFF_SLAB   4496

// X[b][d] -> xt[d][b]; colsum0[d] = sum_b X[b][d]   (R9-proven)
__global__ __launch_bounds__(256) void transpose_kernel(
    const float* __restrict__ X, float* __restrict__ xt,
    float* __restrict__ colsum) {
    const int d = threadIdx.x;
    float cs = 0.0f;
    #pragma unroll
    for (int b = 0; b < B; ++b) {
        const float v = X[b * D + d];
        xt[d * 16 + b] = v;
        cs += v;
    }
    colsum[d] = cs;
}

// Grid: 512 blocks = (node n, e-quarter q). Block: 512 thr = 8 waves.
// Wave w owns d-rows [w*32, w*32+32); lane owns e = e0 + lane.
// Hot loop per d-row: 1 coalesced global_load_dword of W (256 B/wave)
// + 1 striped ds_read_b32 (lane l gets vin[row][l&15]; 16 banks, 4-way
// broadcast = free) + 16 v_readlane + 16 FMA. DS instrs/block: 256 (was
// 1024 b128 = the 5.1 us/CU DS floor that pinned R9/R10/R15 at ~116 us).
__global__ __launch_bounds__(512) void layer_kernel(
    const float* __restrict__ Wl,         // N*D*D (this layer)
    const float* __restrict__ biasl,      // N*D
    const float* __restrict__ Sl,         // N*D
    const float* __restrict__ rhol,       // N
    const float* __restrict__ boostl,     // N
    const int*  __restrict__ tb,
    const float* __restrict__ vin_src,    // [d][b] pre-scaled (xt for l==0)
    const float* __restrict__ colsum,     // [256]
    const float* __restrict__ meta_prev,  // null for l==0
    float* __restrict__ slab,             // [n][4096] tanh'd tiles
    float* __restrict__ fired_cur,        // N
    float depth, int is_first)
{
    __shared__ float vin[D * 16];        // [d][b], 16 KB
    __shared__ float red[8 * 64 * 17];   // [wave][e_loc][b] padded, 34 KB
    __shared__ float sh[8];

    const int t    = threadIdx.x;
    const int w    = t >> 6;
    const int lane = t & 63;
    const int n    = blockIdx.x >> 2;
    const int e0   = (blockIdx.x & 3) * 64;

    // ---- firing preamble from colsum (1 KB) — before any staging
    float part = 0.0f;
    if (t < 256) part = colsum[t] * Sl[n * D + t];
    #pragma unroll
    for (int o = 32; o > 0; o >>= 1) part += __shfl_down(part, o);
    if (lane == 0) sh[w] = part;
    __syncthreads();
    {
        const bool has_input = is_first ? true : (meta_prev[0] > 0.0f);
        const float sdot = (sh[0] + sh[1] + sh[2] + sh[3]) * (1.0f / 16.0f);
        const float tau  = 0.5f * expf(LAMBDA_TAU * (depth - (float)tb[0]));
        const bool fired = (rhol[n] + sdot + boostl[n] >= tau) && has_input;
        if ((blockIdx.x & 3) == 0 && t == 0) fired_cur[n] = fired ? 1.0f : 0.0f;
        if (!fired) return;   // block-uniform: skip staging + W stream
    }

    // ---- stage vin into LDS (16 KB vector copy; only fired blocks)
    {
        const float4* s4 = (const float4*)vin_src;
        ((float4*)vin)[t * 2 + 0] = s4[t * 2 + 0];
        ((float4*)vin)[t * 2 + 1] = s4[t * 2 + 1];
    }
    __syncthreads();

    // ---- main loop: 32 d-rows for this wave
    const int dbase = w * 32;
    const float* wp = Wl + ((size_t)n * D + (size_t)dbase) * D + (e0 + lane);

    float acc[16];
    #pragma unroll
    for (int b = 0; b < 16; ++b) acc[b] = 0.0f;

    #pragma unroll 8
    for (int r = 0; r < 32; ++r) {
        const float wj = wp[(size_t)r * D];                    // 256 B/wave
        const float vv = vin[(dbase + r) * 16 + (lane & 15)];  // striped row
        #pragma unroll
        for (int b = 0; b < 16; ++b) {
            const float rb = __uint_as_float(
                __builtin_amdgcn_readlane(__float_as_uint(vv), b));
            acc[b] = fmaf(wj, rb, acc[b]);
        }
    }

    // ---- cross-wave d-reduce via padded LDS (8 partials per cell)
    {
        float* rr = &red[(w * 64 + lane) * 17];
        #pragma unroll
        for (int b = 0; b < 16; ++b) rr[b] = acc[b];
    }
    __syncthreads();

    // ---- epilogue: thread = (e_loc = t&63, p = t>>6 -> b pair 2p,2p+1)
    {
        const int e_loc = t & 63;
        const int p     = t >> 6;
        float s0 = 0.0f, s1 = 0.0f;
        #pragma unroll
        for (int w2 = 0; w2 < 8; ++w2) {
            const float* rr = &red[(w2 * 64 + e_loc) * 17];
            s0 += rr[2 * p];
            s1 += rr[2 * p + 1];
        }
        const float bv = biasl[n * D + e0 + e_loc];
        float2 o;
        o.x = tanhf(s0 + bv);
        o.y = tanhf(s1 + bv);
        *(float2*)(slab + (size_t)n * 4096 + (size_t)(e0 + e_loc) * 16 + 2 * p) = o;
    }
}

// 64 blocks x 256 thr; thread = (cell, n-chunk of 32). BRANCHLESS (proven).
// acct[c] = scale * sum_n fired[n]*slab[n][c]; colsum[d] = sum_b acct;
// meta[0] = cnt.  IS_FINAL: out[b][e] = sum / max(cnt,1).
template<bool IS_FINAL>
__global__ __launch_bounds__(256) void reduce_kernel(
    const float* __restrict__ slab, const float* __restrict__ fired_l,
    float* __restrict__ acct, float* __restrict__ colsum,
    float* __restrict__ meta, float* __restrict__ out)
{
    __shared__ float part[256];
    __shared__ float shcnt;
    const int t    = threadIdx.x;
    const int cell = blockIdx.x * 64 + (t & 63);
    const int n0   = (t >> 6) * 32;

    float s = 0.0f;
    #pragma unroll 8
    for (int k = 0; k < 32; ++k)
        s = fmaf(fired_l[n0 + k], slab[(size_t)(n0 + k) * 4096 + cell], s);
    part[t] = s;

    if (t < 64) {                             // wave 0: fired count
        float c = fired_l[t] + fired_l[t + 64];
        #pragma unroll
        for (int o = 32; o > 0; o >>= 1) c += __shfl_down(c, o);
        if (t == 0) shcnt = c;
    }
    __syncthreads();

    if (t < 64) {
        const float cnt = shcnt;
        const int c = blockIdx.x * 64 + t;
        const float tot = part[t] + part[64 + t] + part[128 + t] + part[192 + t];
        if (IS_FINAL) {
            out[(c & 15) * 256 + (c >> 4)] = tot / fmaxf(cnt, 1.0f);
        } else {
            const float scale = expf(-LAMBDA_ASYNC) / fmaxf(cnt, 1.0f);
            const float v = tot * scale;
            acct[c] = v;
            float cs = v;                      // colsum over 16 b's per d
            cs += __shfl_down(cs, 8);
            cs += __shfl_down(cs, 4);
            cs += __shfl_down(cs, 2);
            cs += __shfl_down(cs, 1);
            if ((t & 15) == 0) colsum[c >> 4] = cs;
            if (blockIdx.x == 0 && t == 0) meta[0] = cnt;
        }
    }
}

extern "C" void kernel_launch(void* const* d_in, const int* in_sizes, int n_in,
                              void* d_out, int out_size, void* d_ws, size_t ws_size,
                              hipStream_t stream)
{
    const float* X     = (const float*)d_in[0];
    const float* W     = (const float*)d_in[1];
    const float* bias  = (const float*)d_in[2];
    const float* S     = (const float*)d_in[3];
    const float* rho   = (const float*)d_in[4];
    const float* boost = (const float*)d_in[5];
    const int*   tb    = (const int*)d_in[6];
    float* out = (float*)d_out;
    float* ws  = (float*)d_ws;

    float* acct   = ws;
    float* colsum = ws + OFF_COLSUM;
    float* meta   = ws + OFF_META;
    float* fired  = ws + OFF_FIRED;
    float* slab   = ws + OFF_SLAB;

    // xt reuses acct slot (layer 0 stages it before reduce 0 overwrites)
    transpose_kernel<<<dim3(1), dim3(256), 0, stream>>>(X, acct, colsum);

    for (int l = 0; l < L; ++l) {
        layer_kernel<<<dim3(512), dim3(512), 0, stream>>>(
            W + (size_t)l * N * D * D,
            bias + (size_t)l * N * D,
            S + (size_t)l * N * D,
            rho + (size_t)l * N,
            boost + (size_t)l * N,
            tb,
            acct, colsum,
            (l == 0) ? (const float*)nullptr : meta,
            slab, fired,
            (float)(l + 1), (l == 0) ? 1 : 0);
        if (l < L - 1) {
            reduce_kernel<false><<<dim3(64), dim3(256), 0, stream>>>(
                slab, fired, acct, colsum, meta, out);
        } else {
            reduce_kernel<true><<<dim3(64), dim3(256), 0, stream>>>(
                slab, fired, acct, colsum, meta, out);
        }
    }
}